// Round 16
// baseline (44.290 us; speedup 1.0000x reference)
//
#include <hip/hip_runtime.h>
#include <math.h>

#define B_    16
#define N_    6
#define P_    70000
#define H_    112
#define W_    200
#define HW_   (H_ * W_)
#define BSN_  (B_ * N_)
#define HALF_ 56                       // rows per block (H_/2)
#define CELLS_ (HALF_ * W_)            // 11200 cells, 44.8 KB LDS
#define THREADS_ 1024
#define GRP   (4 * THREADS_)           // 4096 points per pipeline group
#define NGRP  17                       // PMAIN / GRP
#define PMAIN (NGRP * GRP)             // 69632
#define PTAIL (P_ - PMAIN)             // 368

// ---------- shared math helpers (identical codegen everywhere) ----------

__device__ __forceinline__ float rdot4(float r0, float r1, float r2, float r3,
                                       float x, float y, float z) {
    float s = r0 * x;
    s = fmaf(r1, y, s);
    s = fmaf(r2, z, s);
    return s + r3;
}

// 4x4 inverse via adjugate (matches jnp.linalg.inv bit-for-bit here — absmax
// 0.0 through rounds 1-15)
__device__ __forceinline__ void inv4(const float* m, float* o) {
    float inv[16];
    inv[0]  =  m[5]*m[10]*m[15] - m[5]*m[11]*m[14] - m[9]*m[6]*m[15] + m[9]*m[7]*m[14] + m[13]*m[6]*m[11] - m[13]*m[7]*m[10];
    inv[4]  = -m[4]*m[10]*m[15] + m[4]*m[11]*m[14] + m[8]*m[6]*m[15] - m[8]*m[7]*m[14] - m[12]*m[6]*m[11] + m[12]*m[7]*m[10];
    inv[8]  =  m[4]*m[9]*m[15]  - m[4]*m[11]*m[13] - m[8]*m[5]*m[15] + m[8]*m[7]*m[13] + m[12]*m[5]*m[11] - m[12]*m[7]*m[9];
    inv[12] = -m[4]*m[9]*m[14]  + m[4]*m[10]*m[13] + m[8]*m[5]*m[14] - m[8]*m[6]*m[13] - m[12]*m[5]*m[10] + m[12]*m[6]*m[9];
    inv[1]  = -m[1]*m[10]*m[15] + m[1]*m[11]*m[14] + m[9]*m[2]*m[15] - m[9]*m[3]*m[14] - m[13]*m[2]*m[11] + m[13]*m[3]*m[10];
    inv[5]  =  m[0]*m[10]*m[15] - m[0]*m[11]*m[14] - m[8]*m[2]*m[15] + m[8]*m[3]*m[14] + m[12]*m[2]*m[11] - m[12]*m[3]*m[10];
    inv[9]  = -m[0]*m[9]*m[15]  + m[0]*m[11]*m[13] + m[8]*m[1]*m[15] - m[8]*m[3]*m[13] - m[12]*m[1]*m[11] + m[12]*m[3]*m[9];
    inv[13] =  m[0]*m[9]*m[14]  - m[0]*m[10]*m[13] - m[8]*m[1]*m[14] + m[8]*m[2]*m[13] + m[12]*m[1]*m[10] - m[12]*m[2]*m[9];
    inv[2]  =  m[1]*m[6]*m[15]  - m[1]*m[7]*m[14]  - m[5]*m[2]*m[15] + m[5]*m[3]*m[14] + m[13]*m[2]*m[7]  - m[13]*m[3]*m[6];
    inv[6]  = -m[0]*m[6]*m[15]  + m[0]*m[7]*m[14]  + m[4]*m[2]*m[15] - m[4]*m[3]*m[14] - m[12]*m[2]*m[7]  + m[12]*m[3]*m[6];
    inv[10] =  m[0]*m[5]*m[15]  - m[0]*m[7]*m[13]  - m[4]*m[1]*m[15] + m[4]*m[3]*m[13] + m[12]*m[1]*m[7]  - m[12]*m[3]*m[5];
    inv[14] = -m[0]*m[5]*m[14]  + m[0]*m[6]*m[13]  + m[4]*m[1]*m[14] - m[4]*m[2]*m[13] - m[12]*m[1]*m[6]  + m[12]*m[2]*m[5];
    inv[3]  = -m[1]*m[6]*m[11]  + m[1]*m[7]*m[10]  + m[5]*m[2]*m[11] - m[5]*m[3]*m[10] - m[9]*m[2]*m[7]   + m[9]*m[3]*m[6];
    inv[7]  =  m[0]*m[6]*m[11]  - m[0]*m[7]*m[10]  - m[4]*m[2]*m[11] + m[4]*m[3]*m[10] + m[8]*m[2]*m[7]   - m[8]*m[3]*m[6];
    inv[11] = -m[0]*m[5]*m[11]  + m[0]*m[7]*m[9]   + m[4]*m[1]*m[11] - m[4]*m[3]*m[9]  - m[8]*m[1]*m[7]   + m[8]*m[3]*m[5];
    inv[15] =  m[0]*m[5]*m[10]  - m[0]*m[6]*m[9]   - m[4]*m[1]*m[10] + m[4]*m[2]*m[9]  + m[8]*m[1]*m[6]   - m[8]*m[2]*m[5];
    float det = m[0]*inv[0] + m[1]*inv[4] + m[2]*inv[8] + m[3]*inv[12];
    float rdet = 1.0f / det;
    for (int i = 0; i < 16; ++i) o[i] = inv[i] * rdet;
}

// Per-camera: Einv (rigid inverse) and PFC = scale_intrinsics4(K) @ Einv.
__device__ __forceinline__ void cam_mats(const float* Ein, const float* Kin,
                                         float E2[4], float PFC[3][4]) {
    float Einv[4][4];
    for (int i = 0; i < 3; ++i)
        for (int j = 0; j < 3; ++j)
            Einv[i][j] = Ein[j * 4 + i];          // R^T
    for (int i = 0; i < 3; ++i) {                  // -(R^T t), asc-j fma
        float s = Ein[0 * 4 + i] * Ein[0 * 4 + 3];
        s = fmaf(Ein[1 * 4 + i], Ein[1 * 4 + 3], s);
        s = fmaf(Ein[2 * 4 + i], Ein[2 * 4 + 3], s);
        Einv[i][3] = -s;
    }
    Einv[3][0] = Ein[12]; Einv[3][1] = Ein[13];
    Einv[3][2] = Ein[14]; Einv[3][3] = Ein[15];

    float K4[4][4] = {};
    K4[0][0] = Kin[0] * 0.25f;  K4[0][2] = Kin[2] * 0.25f;
    K4[1][1] = Kin[4] * 0.25f;  K4[1][2] = Kin[5] * 0.25f;
    K4[2][2] = 1.0f;            K4[3][3] = 1.0f;

    for (int i = 0; i < 3; ++i)
        for (int j = 0; j < 4; ++j) {
            float s = K4[i][0] * Einv[0][j];
            s = fmaf(K4[i][1], Einv[1][j], s);
            s = fmaf(K4[i][2], Einv[2][j], s);
            s = fmaf(K4[i][3], Einv[3][j], s);
            PFC[i][j] = s;
        }
    for (int j = 0; j < 4; ++j) E2[j] = Einv[2][j];
}

// ---------- fused kernel: one block per (camera m, row-half) ----------
// R15 + (a) __launch_bounds__(1024,4): grid is 192 blocks = 1 block/CU =
// 4 waves/SIMD exactly, so declare it -> VGPR cap rises ~32 -> ~128 and the
// compiler can keep matrices + pipeline registers live (R15 compiled at
// VGPR=36: matrices demoted to LDS, pipeline flattened, ~1000cyc serial
// load->use chain per iteration remained the floor).
// (b) depth-8 pipeline: two 4096-pt groups in flight (12 live float4 = 48
// VGPR + 24 matrix + addr ~= 80 < 128).

__global__ __launch_bounds__(THREADS_, 4) void k_lidar_pipe2(
        const float4* __restrict__ pc, const float* __restrict__ extr,
        const float* __restrict__ intr, const float* __restrict__ view,
        float* __restrict__ out, const int* __restrict__ bev_side_p) {
    __shared__ int   win[CELLS_];      // 44.8 KB
    __shared__ float sM[28];           // 0..11 Vinv, 12..23 PFC, 24..27 E2

    // XCD swizzle: co-locate all 12 blocks of one batch on one XCD.
    const int i    = blockIdx.x;       // 0..191
    const int xcd  = i & 7;
    const int s    = i >> 3;           // 0..23
    const int b    = xcd + 8 * (s >= 12 ? 1 : 0);
    const int c12  = s % 12;
    const int m    = b * N_ + (c12 >> 1);
    const int half = c12 & 1;
    const int rlo  = half * HALF_;
    const int t    = threadIdx.x;

    if (t == 0) {                      // wave 0: Vinv
        float Vi[16];
        inv4(&view[b * 16], Vi);
        for (int k = 0; k < 12; ++k) sM[k] = Vi[k];
    } else if (t == 64) {              // wave 1: this camera
        float E2[4], PFC[3][4];
        cam_mats(&extr[m * 16], &intr[m * 9], E2, PFC);
        for (int ii = 0; ii < 3; ++ii)
            for (int jj = 0; jj < 4; ++jj) sM[12 + ii * 4 + jj] = PFC[ii][jj];
        for (int jj = 0; jj < 4; ++jj) sM[24 + jj] = E2[jj];
    }
    for (int k = t; k < CELLS_; k += THREADS_) win[k] = -1;
    __syncthreads();

    // hoist matrices to registers
    const float V0 = sM[0],  V1 = sM[1],  V2 = sM[2],  V3 = sM[3];
    const float V4 = sM[4],  V5 = sM[5],  V6 = sM[6],  V7 = sM[7];
    const float V8 = sM[8],  V9 = sM[9],  V10 = sM[10], V11 = sM[11];
    const float P00 = sM[12], P01 = sM[13], P02 = sM[14], P03 = sM[15];
    const float P10 = sM[16], P11 = sM[17], P12 = sM[18], P13 = sM[19];
    const float P20 = sM[20], P21 = sM[21], P22 = sM[22], P23 = sM[23];

    const float4* pcb = pc + (size_t)b * P_;
    int cA = -1, cB = -1;              // this half's two corner winners

    // per-point phase-A body: R12/R14-verified conservative screens.
    //   px <= 0.99*denom => xm==0 ; px >= 201*denom => xm==199 (y: 0.99/113)
    // Certain own-half corners -> register max (p ascending => assign=max).
    // Uncertain (~1%) -> exact reference divide/clip + LDS atomicMax.
#define PROC(PT, PIDX)                                                        \
    {                                                                         \
        float lx = rdot4(V0, V1, V2,  V3,  (PT).x, (PT).y, (PT).z);           \
        float ly = rdot4(V4, V5, V6,  V7,  (PT).x, (PT).y, (PT).z);           \
        float lz = rdot4(V8, V9, V10, V11, (PT).x, (PT).y, (PT).z);           \
        float px = rdot4(P00, P01, P02, P03, lx, ly, lz);                     \
        float py = rdot4(P10, P11, P12, P13, lx, ly, lz);                     \
        float pz = rdot4(P20, P21, P22, P23, lx, ly, lz);                     \
        float denom = fmaxf(pz, 1e-6f);                                       \
        bool x0 = (px <= 0.99f  * denom);                                     \
        bool x1 = (px >= 201.0f * denom);                                     \
        bool y0 = (py <= 0.99f  * denom);                                     \
        bool y1 = (py >= 113.0f * denom);                                     \
        bool yh = half ? y1 : y0;                                             \
        cA = (x0 & yh) ? (PIDX) : cA;                                         \
        cB = (x1 & yh) ? (PIDX) : cB;                                         \
        if (!((x0 | x1) & (y0 | y1))) {                                       \
            float x_ = px / denom;                                            \
            float y_ = py / denom;                                            \
            int ym = (int)fminf(fmaxf(y_, 0.0f), (float)(H_ - 1));            \
            int xm = (int)fminf(fmaxf(x_, 0.0f), (float)(W_ - 1));            \
            bool is_c = (xm == 0 || xm == W_ - 1) &&                          \
                        (ym == 0 || ym == H_ - 1);                            \
            int rr = ym - rlo;                                                \
            if ((unsigned)rr < (unsigned)HALF_) {                             \
                if (is_c) {                                                   \
                    bool right = (xm != 0);                                   \
                    cA = (!right) ? max(cA, (PIDX)) : cA;                     \
                    cB = ( right) ? max(cB, (PIDX)) : cB;                     \
                } else {                                                      \
                    atomicMax(&win[rr * W_ + xm], (PIDX));                    \
                }                                                             \
            }                                                                 \
        }                                                                     \
    }

#define LOADG(DST0, DST1, DST2, DST3, GB)                                     \
        DST0 = pcb[(GB) + t];                                                 \
        DST1 = pcb[(GB) + t + THREADS_];                                      \
        DST2 = pcb[(GB) + t + 2 * THREADS_];                                  \
        DST3 = pcb[(GB) + t + 3 * THREADS_];

#define PROCG(SRC0, SRC1, SRC2, SRC3, GB)                                     \
        PROC(SRC0, (GB) + t)                                                  \
        PROC(SRC1, (GB) + t + THREADS_)                                       \
        PROC(SRC2, (GB) + t + 2 * THREADS_)                                   \
        PROC(SRC3, (GB) + t + 3 * THREADS_)

    // ---- Phase A: depth-8 pipeline (two groups in flight) over 17 groups --
    float4 q0, q1, q2, q3, n0, n1, n2, n3;
    LOADG(q0, q1, q2, q3, 0)
    LOADG(n0, n1, n2, n3, GRP)
    for (int g = 0; g + 2 < NGRP; ++g) {
        const int gbase = g * GRP;
        // issue group g+2's loads FIRST; pin above group g's compute
        float4 f0, f1, f2, f3;
        LOADG(f0, f1, f2, f3, gbase + 2 * GRP)
        __builtin_amdgcn_sched_barrier(0);
        PROCG(q0, q1, q2, q3, gbase)
        q0 = n0; q1 = n1; q2 = n2; q3 = n3;
        n0 = f0; n1 = f1; n2 = f2; n3 = f3;
    }
    PROCG(q0, q1, q2, q3, (NGRP - 2) * GRP)
    PROCG(n0, n1, n2, n3, (NGRP - 1) * GRP)
    if (t < PTAIL) {                   // tail: points 69632..69999 (ascending)
        float4 q = pcb[PMAIN + t];
        PROC(q, PMAIN + t)
    }
#undef PROCG
#undef LOADG
#undef PROC

    // wave-reduce corner maxima, then one LDS atomic per wave per corner
    for (int d = 32; d; d >>= 1) {
        cA = max(cA, __shfl_xor(cA, d));
        cB = max(cB, __shfl_xor(cB, d));
    }
    if ((t & 63) == 0) {
        int cell0 = half ? (HALF_ - 1) * W_ : 0;
        if (cA >= 0) atomicMax(&win[cell0],          cA);
        if (cB >= 0) atomicMax(&win[cell0 + W_ - 1], cB);
    }
    __syncthreads();

    // ---- Phase B: finalize (bit-exact path, proven rounds 1-15) ----
    const float bev_half = (float)bev_side_p[0] * 0.5f;   // 100.0
    const float clip_hi  = bev_half - 1.0f;               // 99.0
    const float E20 = sM[24], E21 = sM[25], E22 = sM[26], E23 = sM[27];
    const int base0 = (m * 2) * HW_ + rlo * W_;
    for (int r = t; r < CELLS_; r += THREADS_) {
        int w = win[r];
        float depth = 0.0f, iluv = 0.0f;
        if (w >= 0) {
            float4 pt = pcb[w];
            float lx = rdot4(V0, V1, V2,  V3,  pt.x, pt.y, pt.z);
            float ly = rdot4(V4, V5, V6,  V7,  pt.x, pt.y, pt.z);
            float lz = rdot4(V8, V9, V10, V11, pt.x, pt.y, pt.z);
            float z  = rdot4(E20, E21, E22, E23, lx, ly, lz);
            float px = rdot4(P00, P01, P02, P03, lx, ly, lz);
            float py = rdot4(P10, P11, P12, P13, lx, ly, lz);
            float pz = rdot4(P20, P21, P22, P23, lx, ly, lz);
            float denom = fmaxf(pz, 1e-6f);
            float x_ = px / denom;
            float y_ = py / denom;
            bool valid = (x_ > -0.5f) && (x_ < (float)W_ - 0.5f) &&
                         (y_ > -0.5f) && (y_ < (float)H_ - 0.5f) && (z > 0.0f);
            if (valid) {
                float d = fminf(fmaxf(pz, 0.0f), clip_hi);     // clip(normalizer,0,99)
                depth = d / bev_half;                           // /100
                float vi = fminf(fmaxf(pt.w, 0.0f), 255.0f);    // clip(ilu,0,255)
                iluv = log1pf(vi) / 5.545177444479562f;         // /log(256) as f32
            }
        }
        out[base0 + r]       = depth;
        out[base0 + HW_ + r] = iluv;
    }
}

// ---------- launch ----------

extern "C" void kernel_launch(void* const* d_in, const int* in_sizes, int n_in,
                              void* d_out, int out_size, void* d_ws, size_t ws_size,
                              hipStream_t stream) {
    const float4* pc  = (const float4*)d_in[0];
    const float* extr = (const float*)d_in[1];
    const float* intr = (const float*)d_in[2];
    const float* view = (const float*)d_in[3];
    const int*   bev  = (const int*)d_in[4];
    float* out = (float*)d_out;

    k_lidar_pipe2<<<dim3(BSN_ * 2), dim3(THREADS_), 0, stream>>>(
        pc, extr, intr, view, out, bev);
}

// Round 17
// 42.926 us; speedup vs baseline: 1.0318x; 1.0318x over previous
//
#include <hip/hip_runtime.h>
#include <math.h>

#define B_    16
#define N_    6
#define P_    70000
#define H_    112
#define W_    200
#define HW_   (H_ * W_)
#define BSN_  (B_ * N_)
#define HALF_ 56                       // rows per half-grid
#define CELLS_ (HALF_ * W_)            // 11200 cells, 44.8 KB LDS
#define NSEG  4
#define SEGPTS (P_ / NSEG)             // 17500
#define T1_   512                      // k_partial2 threads (8 waves)
#define T2_   1024                     // k_mergefin threads

// ws: int partial[96][2][NSEG][CELLS_] = 34.4 MB, fully written by K1
#define WS_NEED ((size_t)BSN_ * 2 * NSEG * CELLS_ * 4)

// ---------- shared math helpers (identical codegen everywhere) ----------

__device__ __forceinline__ float rdot4(float r0, float r1, float r2, float r3,
                                       float x, float y, float z) {
    float s = r0 * x;
    s = fmaf(r1, y, s);
    s = fmaf(r2, z, s);
    return s + r3;
}

// 4x4 inverse via adjugate (matches jnp.linalg.inv bit-for-bit here — absmax
// 0.0 through rounds 1-16)
__device__ __forceinline__ void inv4(const float* m, float* o) {
    float inv[16];
    inv[0]  =  m[5]*m[10]*m[15] - m[5]*m[11]*m[14] - m[9]*m[6]*m[15] + m[9]*m[7]*m[14] + m[13]*m[6]*m[11] - m[13]*m[7]*m[10];
    inv[4]  = -m[4]*m[10]*m[15] + m[4]*m[11]*m[14] + m[8]*m[6]*m[15] - m[8]*m[7]*m[14] - m[12]*m[6]*m[11] + m[12]*m[7]*m[10];
    inv[8]  =  m[4]*m[9]*m[15]  - m[4]*m[11]*m[13] - m[8]*m[5]*m[15] + m[8]*m[7]*m[13] + m[12]*m[5]*m[11] - m[12]*m[7]*m[9];
    inv[12] = -m[4]*m[9]*m[14]  + m[4]*m[10]*m[13] + m[8]*m[5]*m[14] - m[8]*m[6]*m[13] - m[12]*m[5]*m[10] + m[12]*m[6]*m[9];
    inv[1]  = -m[1]*m[10]*m[15] + m[1]*m[11]*m[14] + m[9]*m[2]*m[15] - m[9]*m[3]*m[14] - m[13]*m[2]*m[11] + m[13]*m[3]*m[10];
    inv[5]  =  m[0]*m[10]*m[15] - m[0]*m[11]*m[14] - m[8]*m[2]*m[15] + m[8]*m[3]*m[14] + m[12]*m[2]*m[11] - m[12]*m[3]*m[10];
    inv[9]  = -m[0]*m[9]*m[15]  + m[0]*m[11]*m[13] + m[8]*m[1]*m[15] - m[8]*m[3]*m[13] - m[12]*m[1]*m[11] + m[12]*m[3]*m[9];
    inv[13] =  m[0]*m[9]*m[14]  - m[0]*m[10]*m[13] - m[8]*m[1]*m[14] + m[8]*m[2]*m[13] + m[12]*m[1]*m[10] - m[12]*m[2]*m[9];
    inv[2]  =  m[1]*m[6]*m[15]  - m[1]*m[7]*m[14]  - m[5]*m[2]*m[15] + m[5]*m[3]*m[14] + m[13]*m[2]*m[7]  - m[13]*m[3]*m[6];
    inv[6]  = -m[0]*m[6]*m[15]  + m[0]*m[7]*m[14]  + m[4]*m[2]*m[15] - m[4]*m[3]*m[14] - m[12]*m[2]*m[7]  + m[12]*m[3]*m[6];
    inv[10] =  m[0]*m[5]*m[15]  - m[0]*m[7]*m[13]  - m[4]*m[1]*m[15] + m[4]*m[3]*m[13] + m[12]*m[1]*m[7]  - m[12]*m[3]*m[5];
    inv[14] = -m[0]*m[5]*m[14]  + m[0]*m[6]*m[13]  + m[4]*m[1]*m[14] - m[4]*m[2]*m[13] - m[12]*m[1]*m[6]  + m[12]*m[2]*m[5];
    inv[3]  = -m[1]*m[6]*m[11]  + m[1]*m[7]*m[10]  + m[5]*m[2]*m[11] - m[5]*m[3]*m[10] - m[9]*m[2]*m[7]   + m[9]*m[3]*m[6];
    inv[7]  =  m[0]*m[6]*m[11]  - m[0]*m[7]*m[10]  - m[4]*m[2]*m[11] + m[4]*m[3]*m[10] + m[8]*m[2]*m[7]   - m[8]*m[3]*m[6];
    inv[11] = -m[0]*m[5]*m[11]  + m[0]*m[7]*m[9]   + m[4]*m[1]*m[11] - m[4]*m[3]*m[9]  - m[8]*m[1]*m[7]   + m[8]*m[3]*m[5];
    inv[15] =  m[0]*m[5]*m[10]  - m[0]*m[6]*m[9]   - m[4]*m[1]*m[10] + m[4]*m[2]*m[9]  + m[8]*m[1]*m[6]   - m[8]*m[2]*m[5];
    float det = m[0]*inv[0] + m[1]*inv[4] + m[2]*inv[8] + m[3]*inv[12];
    float rdet = 1.0f / det;
    for (int i = 0; i < 16; ++i) o[i] = inv[i] * rdet;
}

// Per-camera: Einv (rigid inverse) and PFC = scale_intrinsics4(K) @ Einv.
__device__ __forceinline__ void cam_mats(const float* Ein, const float* Kin,
                                         float E2[4], float PFC[3][4]) {
    float Einv[4][4];
    for (int i = 0; i < 3; ++i)
        for (int j = 0; j < 3; ++j)
            Einv[i][j] = Ein[j * 4 + i];          // R^T
    for (int i = 0; i < 3; ++i) {                  // -(R^T t), asc-j fma
        float s = Ein[0 * 4 + i] * Ein[0 * 4 + 3];
        s = fmaf(Ein[1 * 4 + i], Ein[1 * 4 + 3], s);
        s = fmaf(Ein[2 * 4 + i], Ein[2 * 4 + 3], s);
        Einv[i][3] = -s;
    }
    Einv[3][0] = Ein[12]; Einv[3][1] = Ein[13];
    Einv[3][2] = Ein[14]; Einv[3][3] = Ein[15];

    float K4[4][4] = {};
    K4[0][0] = Kin[0] * 0.25f;  K4[0][2] = Kin[2] * 0.25f;
    K4[1][1] = Kin[4] * 0.25f;  K4[1][2] = Kin[5] * 0.25f;
    K4[2][2] = 1.0f;            K4[3][3] = 1.0f;

    for (int i = 0; i < 3; ++i)
        for (int j = 0; j < 4; ++j) {
            float s = K4[i][0] * Einv[0][j];
            s = fmaf(K4[i][1], Einv[1][j], s);
            s = fmaf(K4[i][2], Einv[2][j], s);
            s = fmaf(K4[i][3], Einv[3][j], s);
            PFC[i][j] = s;
        }
    for (int j = 0; j < 4; ++j) E2[j] = Einv[2][j];
}

// ---------- K1: screened partial winner grids. Block = (cam, half, seg) ----
// 768 blocks x 512 threads, 44.8 KB LDS, __launch_bounds__(512,6) ->
// 3 blocks/CU co-resident = 6 waves/SIMD (vs R15's 4) hiding L2 latency,
// AND R14's screens cut per-visit issue ~3x. Both levers combined for the
// first time. No device atomics; partials dumped with plain stores.

__global__ __launch_bounds__(T1_, 6) void k_partial2(
        const float4* __restrict__ pc, const float* __restrict__ extr,
        const float* __restrict__ intr, const float* __restrict__ view,
        int* __restrict__ partial) {
    __shared__ int   win[CELLS_];      // 44.8 KB
    __shared__ float sM[24];           // 0..11 Vinv, 12..23 PFC

    // XCD swizzle: 768 blocks, 96/XCD = 2 batches' worth (48 blocks/batch)
    const int i    = blockIdx.x;
    const int xcd  = i & 7;
    const int j    = i >> 3;           // 0..95
    const int b    = xcd + 8 * (j >= 48 ? 1 : 0);
    const int r    = j % 48;
    const int cam  = r >> 3;           // /8 (2 half x 4 seg)
    const int half = (r >> 2) & 1;
    const int seg  = r & 3;
    const int m    = b * N_ + cam;
    const int rlo  = half * HALF_;
    const int t    = threadIdx.x;

    if (t == 0) {                      // wave 0: Vinv
        float Vi[16];
        inv4(&view[b * 16], Vi);
        for (int k = 0; k < 12; ++k) sM[k] = Vi[k];
    } else if (t == 64) {              // wave 1: this camera's PFC
        float E2[4], PFC[3][4];
        cam_mats(&extr[m * 16], &intr[m * 9], E2, PFC);
        for (int ii = 0; ii < 3; ++ii)
            for (int jj = 0; jj < 4; ++jj) sM[12 + ii * 4 + jj] = PFC[ii][jj];
    }
    for (int k = t; k < CELLS_; k += T1_) win[k] = -1;
    __syncthreads();

    const float V0 = sM[0],  V1 = sM[1],  V2 = sM[2],  V3 = sM[3];
    const float V4 = sM[4],  V5 = sM[5],  V6 = sM[6],  V7 = sM[7];
    const float V8 = sM[8],  V9 = sM[9],  V10 = sM[10], V11 = sM[11];
    const float P00 = sM[12], P01 = sM[13], P02 = sM[14], P03 = sM[15];
    const float P10 = sM[16], P11 = sM[17], P12 = sM[18], P13 = sM[19];
    const float P20 = sM[20], P21 = sM[21], P22 = sM[22], P23 = sM[23];

    const float4* pcb = pc + (size_t)b * P_;
    int cA = -1, cB = -1;              // this half's two corner winners
    const int p0 = seg * SEGPTS;

    // R12/R14-verified conservative screens on exact px,py,denom:
    //   px<=0.99*denom => xm==0 ; px>=201*denom => xm==199 (y: 0.99 / 113)
    // Certain own-half corners -> register max (p ascending => assign=max).
    // Uncertain (~1%) -> exact reference divide/clip + LDS atomicMax.
    for (int p = p0 + t; p < p0 + SEGPTS; p += T1_) {   // p ascending/thread
        float4 pt = pcb[p];
        float lx = rdot4(V0, V1, V2,  V3,  pt.x, pt.y, pt.z);
        float ly = rdot4(V4, V5, V6,  V7,  pt.x, pt.y, pt.z);
        float lz = rdot4(V8, V9, V10, V11, pt.x, pt.y, pt.z);
        float px = rdot4(P00, P01, P02, P03, lx, ly, lz);
        float py = rdot4(P10, P11, P12, P13, lx, ly, lz);
        float pz = rdot4(P20, P21, P22, P23, lx, ly, lz);
        float denom = fmaxf(pz, 1e-6f);
        bool x0 = (px <= 0.99f  * denom);
        bool x1 = (px >= 201.0f * denom);
        bool y0 = (py <= 0.99f  * denom);
        bool y1 = (py >= 113.0f * denom);
        bool yh = half ? y1 : y0;                 // own-half certain y
        cA = (x0 & yh) ? p : cA;
        cB = (x1 & yh) ? p : cB;
        if (!((x0 | x1) & (y0 | y1))) {           // uncertain -> exact path
            float x_ = px / denom;                // reference sequence
            float y_ = py / denom;
            int ym = (int)fminf(fmaxf(y_, 0.0f), (float)(H_ - 1));
            int xm = (int)fminf(fmaxf(x_, 0.0f), (float)(W_ - 1));
            bool is_c = (xm == 0 || xm == W_ - 1) && (ym == 0 || ym == H_ - 1);
            int rr = ym - rlo;
            if ((unsigned)rr < (unsigned)HALF_) {
                if (is_c) {
                    bool right = (xm != 0);
                    cA = (!right) ? max(cA, p) : cA;
                    cB = ( right) ? max(cB, p) : cB;
                } else {
                    atomicMax(&win[rr * W_ + xm], p);
                }
            }
        }
    }
    // wave-reduce corner maxima, one LDS atomic per wave per corner
    for (int d = 32; d; d >>= 1) {
        cA = max(cA, __shfl_xor(cA, d));
        cB = max(cB, __shfl_xor(cB, d));
    }
    if ((t & 63) == 0) {
        int cell0 = half ? (HALF_ - 1) * W_ : 0;
        if (cA >= 0) atomicMax(&win[cell0],          cA);
        if (cB >= 0) atomicMax(&win[cell0 + W_ - 1], cB);
    }
    __syncthreads();

    // dump partial grid (plain coalesced stores)
    int* dst = partial + (size_t)(((m * 2 + half) * NSEG) + seg) * CELLS_;
    for (int k = t; k < CELLS_; k += T1_) dst[k] = win[k];
}

// ---------- K2: merge 4 partials + finalize (R11's kernel, absmax 0.0) ----

__global__ __launch_bounds__(T2_) void k_mergefin(
        const float4* __restrict__ pc, const int* __restrict__ partial,
        const float* __restrict__ extr, const float* __restrict__ intr,
        const float* __restrict__ view,
        float* __restrict__ out, const int* __restrict__ bev_side_p) {
    __shared__ float sM[28];           // 0..11 Vinv, 12..23 PFC, 24..27 E2

    const int i    = blockIdx.x;
    const int xcd  = i & 7;
    const int j    = i >> 3;           // 0..23
    const int b    = xcd + 8 * (j >= 12 ? 1 : 0);
    const int r    = j % 12;
    const int cam  = r >> 1;
    const int half = r & 1;
    const int m    = b * N_ + cam;
    const int rlo  = half * HALF_;
    const int t    = threadIdx.x;

    if (t == 0) {
        float Vi[16];
        inv4(&view[b * 16], Vi);
        for (int k = 0; k < 12; ++k) sM[k] = Vi[k];
    } else if (t == 64) {
        float E2[4], PFC[3][4];
        cam_mats(&extr[m * 16], &intr[m * 9], E2, PFC);
        for (int ii = 0; ii < 3; ++ii)
            for (int jj = 0; jj < 4; ++jj) sM[12 + ii * 4 + jj] = PFC[ii][jj];
        for (int jj = 0; jj < 4; ++jj) sM[24 + jj] = E2[jj];
    }
    __syncthreads();

    const float bev_half = (float)bev_side_p[0] * 0.5f;   // 100.0
    const float clip_hi  = bev_half - 1.0f;               // 99.0
    const float4* pcb = pc + (size_t)b * P_;
    const int* pp = partial + (size_t)((m * 2 + half) * NSEG) * CELLS_;
    const int base0 = (m * 2) * HW_ + rlo * W_;

    for (int rr = t; rr < CELLS_; rr += T2_) {
        int wv = max(max(pp[rr], pp[CELLS_ + rr]),
                     max(pp[2 * CELLS_ + rr], pp[3 * CELLS_ + rr]));
        float depth = 0.0f, iluv = 0.0f;
        if (wv >= 0) {
            float4 pt = pcb[wv];
            float lx = rdot4(sM[0],  sM[1],  sM[2],  sM[3],  pt.x, pt.y, pt.z);
            float ly = rdot4(sM[4],  sM[5],  sM[6],  sM[7],  pt.x, pt.y, pt.z);
            float lz = rdot4(sM[8],  sM[9],  sM[10], sM[11], pt.x, pt.y, pt.z);
            float z  = rdot4(sM[24], sM[25], sM[26], sM[27], lx, ly, lz);
            float px = rdot4(sM[12], sM[13], sM[14], sM[15], lx, ly, lz);
            float py = rdot4(sM[16], sM[17], sM[18], sM[19], lx, ly, lz);
            float pz = rdot4(sM[20], sM[21], sM[22], sM[23], lx, ly, lz);
            float denom = fmaxf(pz, 1e-6f);
            float x_ = px / denom;
            float y_ = py / denom;
            bool valid = (x_ > -0.5f) && (x_ < (float)W_ - 0.5f) &&
                         (y_ > -0.5f) && (y_ < (float)H_ - 0.5f) && (z > 0.0f);
            if (valid) {
                float d = fminf(fmaxf(pz, 0.0f), clip_hi);     // clip(normalizer,0,99)
                depth = d / bev_half;                           // /100
                float vi = fminf(fmaxf(pt.w, 0.0f), 255.0f);    // clip(ilu,0,255)
                iluv = log1pf(vi) / 5.545177444479562f;         // /log(256) as f32
            }
        }
        out[base0 + rr]       = depth;
        out[base0 + HW_ + rr] = iluv;
    }
}

// ---------- fallback (R15 single-kernel path, if ws too small) ----------

__global__ __launch_bounds__(1024) void k_lidar_scr(
        const float4* __restrict__ pc, const float* __restrict__ extr,
        const float* __restrict__ intr, const float* __restrict__ view,
        float* __restrict__ out, const int* __restrict__ bev_side_p) {
    __shared__ int   win[CELLS_];
    __shared__ float sM[28];

    const int i    = blockIdx.x;
    const int xcd  = i & 7;
    const int s    = i >> 3;
    const int b    = xcd + 8 * (s >= 12 ? 1 : 0);
    const int c12  = s % 12;
    const int m    = b * N_ + (c12 >> 1);
    const int half = c12 & 1;
    const int rlo  = half * HALF_;
    const int t    = threadIdx.x;

    if (t == 0) {
        float Vi[16];
        inv4(&view[b * 16], Vi);
        for (int k = 0; k < 12; ++k) sM[k] = Vi[k];
    } else if (t == 64) {
        float E2[4], PFC[3][4];
        cam_mats(&extr[m * 16], &intr[m * 9], E2, PFC);
        for (int ii = 0; ii < 3; ++ii)
            for (int jj = 0; jj < 4; ++jj) sM[12 + ii * 4 + jj] = PFC[ii][jj];
        for (int jj = 0; jj < 4; ++jj) sM[24 + jj] = E2[jj];
    }
    for (int k = t; k < CELLS_; k += 1024) win[k] = -1;
    __syncthreads();

    const float V0 = sM[0],  V1 = sM[1],  V2 = sM[2],  V3 = sM[3];
    const float V4 = sM[4],  V5 = sM[5],  V6 = sM[6],  V7 = sM[7];
    const float V8 = sM[8],  V9 = sM[9],  V10 = sM[10], V11 = sM[11];
    const float P00 = sM[12], P01 = sM[13], P02 = sM[14], P03 = sM[15];
    const float P10 = sM[16], P11 = sM[17], P12 = sM[18], P13 = sM[19];
    const float P20 = sM[20], P21 = sM[21], P22 = sM[22], P23 = sM[23];

    const float4* pcb = pc + (size_t)b * P_;
    int cA = -1, cB = -1;

    for (int p = t; p < P_; p += 1024) {
        float4 pt = pcb[p];
        float lx = rdot4(V0, V1, V2,  V3,  pt.x, pt.y, pt.z);
        float ly = rdot4(V4, V5, V6,  V7,  pt.x, pt.y, pt.z);
        float lz = rdot4(V8, V9, V10, V11, pt.x, pt.y, pt.z);
        float px = rdot4(P00, P01, P02, P03, lx, ly, lz);
        float py = rdot4(P10, P11, P12, P13, lx, ly, lz);
        float pz = rdot4(P20, P21, P22, P23, lx, ly, lz);
        float denom = fmaxf(pz, 1e-6f);
        bool x0 = (px <= 0.99f  * denom);
        bool x1 = (px >= 201.0f * denom);
        bool y0 = (py <= 0.99f  * denom);
        bool y1 = (py >= 113.0f * denom);
        bool yh = half ? y1 : y0;
        cA = (x0 & yh) ? p : cA;
        cB = (x1 & yh) ? p : cB;
        if (!((x0 | x1) & (y0 | y1))) {
            float x_ = px / denom;
            float y_ = py / denom;
            int ym = (int)fminf(fmaxf(y_, 0.0f), (float)(H_ - 1));
            int xm = (int)fminf(fmaxf(x_, 0.0f), (float)(W_ - 1));
            bool is_c = (xm == 0 || xm == W_ - 1) && (ym == 0 || ym == H_ - 1);
            int rr = ym - rlo;
            if ((unsigned)rr < (unsigned)HALF_) {
                if (is_c) {
                    bool right = (xm != 0);
                    cA = (!right) ? max(cA, p) : cA;
                    cB = ( right) ? max(cB, p) : cB;
                } else {
                    atomicMax(&win[rr * W_ + xm], p);
                }
            }
        }
    }
    for (int d = 32; d; d >>= 1) {
        cA = max(cA, __shfl_xor(cA, d));
        cB = max(cB, __shfl_xor(cB, d));
    }
    if ((t & 63) == 0) {
        int cell0 = half ? (HALF_ - 1) * W_ : 0;
        if (cA >= 0) atomicMax(&win[cell0],          cA);
        if (cB >= 0) atomicMax(&win[cell0 + W_ - 1], cB);
    }
    __syncthreads();

    const float bev_half = (float)bev_side_p[0] * 0.5f;
    const float clip_hi  = bev_half - 1.0f;
    const float E20 = sM[24], E21 = sM[25], E22 = sM[26], E23 = sM[27];
    const int base0 = (m * 2) * HW_ + rlo * W_;
    for (int r = t; r < CELLS_; r += 1024) {
        int w = win[r];
        float depth = 0.0f, iluv = 0.0f;
        if (w >= 0) {
            float4 pt = pcb[w];
            float lx = rdot4(V0, V1, V2,  V3,  pt.x, pt.y, pt.z);
            float ly = rdot4(V4, V5, V6,  V7,  pt.x, pt.y, pt.z);
            float lz = rdot4(V8, V9, V10, V11, pt.x, pt.y, pt.z);
            float z  = rdot4(E20, E21, E22, E23, lx, ly, lz);
            float px = rdot4(P00, P01, P02, P03, lx, ly, lz);
            float py = rdot4(P10, P11, P12, P13, lx, ly, lz);
            float pz = rdot4(P20, P21, P22, P23, lx, ly, lz);
            float denom = fmaxf(pz, 1e-6f);
            float x_ = px / denom;
            float y_ = py / denom;
            bool valid = (x_ > -0.5f) && (x_ < (float)W_ - 0.5f) &&
                         (y_ > -0.5f) && (y_ < (float)H_ - 0.5f) && (z > 0.0f);
            if (valid) {
                float d = fminf(fmaxf(pz, 0.0f), clip_hi);
                depth = d / bev_half;
                float vi = fminf(fmaxf(pt.w, 0.0f), 255.0f);
                iluv = log1pf(vi) / 5.545177444479562f;
            }
        }
        out[base0 + r]       = depth;
        out[base0 + HW_ + r] = iluv;
    }
}

// ---------- launch ----------

extern "C" void kernel_launch(void* const* d_in, const int* in_sizes, int n_in,
                              void* d_out, int out_size, void* d_ws, size_t ws_size,
                              hipStream_t stream) {
    const float4* pc  = (const float4*)d_in[0];
    const float* extr = (const float*)d_in[1];
    const float* intr = (const float*)d_in[2];
    const float* view = (const float*)d_in[3];
    const int*   bev  = (const int*)d_in[4];
    float* out = (float*)d_out;

    if (ws_size >= WS_NEED) {
        int* partial = (int*)d_ws;
        k_partial2<<<dim3(BSN_ * 2 * NSEG), dim3(T1_), 0, stream>>>(
            pc, extr, intr, view, partial);
        k_mergefin<<<dim3(BSN_ * 2), dim3(T2_), 0, stream>>>(
            pc, partial, extr, intr, view, out, bev);
    } else {
        k_lidar_scr<<<dim3(BSN_ * 2), dim3(1024), 0, stream>>>(
            pc, extr, intr, view, out, bev);
    }
}